// Round 12
// baseline (120.440 us; speedup 1.0000x reference)
//
#include <hip/hip_runtime.h>
#include <hip/hip_bf16.h>
#include <math.h>

// Problem constants
#define BATCH 2
#define SEQ   2048
#define EMB   1024
#define NH    16
#define HD    64
#define M_ROWS (BATCH * SEQ)   // 4096

typedef __attribute__((ext_vector_type(8))) short bf16x8;
typedef __attribute__((ext_vector_type(4))) float f32x4;

// fp32 -> bf16 round-to-nearest-even, raw bits
__device__ __forceinline__ ushort f2bf(float f) {
    unsigned u = __float_as_uint(f);
    unsigned lsb = (u >> 16) & 1u;
    u += 0x7fffu + lsb;
    return (ushort)(u >> 16);
}

// packed f32 pair -> 2 bf16 in one u32 (RNE), single VALU op
__device__ __forceinline__ unsigned cvt_pk_bf16(float lo, float hi) {
    unsigned r;
    asm("v_cvt_pk_bf16_f32 %0, %1, %2" : "=v"(r) : "v"(lo), "v"(hi));
    return r;
}

__device__ __forceinline__ void gload_lds16(const void* g, void* l) {
    __builtin_amdgcn_global_load_lds(
        (const __attribute__((address_space(1))) unsigned int*)g,
        (__attribute__((address_space(3))) unsigned int*)l, 16, 0, 0);
}

// ---------------------------------------------------------------------------
// fused fp32 -> bf16 conversion of x, qkv_w, o_w (outputs contiguous in ws)
// ---------------------------------------------------------------------------
__global__ __launch_bounds__(256) void cvt3_f32_bf16(
    const float* __restrict__ s1, const float* __restrict__ s2,
    const float* __restrict__ s3, ushort* __restrict__ out,
    int n1, int n2)
{
    int i = (blockIdx.x * 256 + threadIdx.x) * 4;
    const float* src;
    int off;
    if (i < n1)            { src = s1; off = i; }
    else if (i < n1 + n2)  { src = s2; off = i - n1; }
    else                   { src = s3; off = i - n1 - n2; }
    float4 v = *reinterpret_cast<const float4*>(&src[off]);
    uint2 pk;
    pk.x = cvt_pk_bf16(v.x, v.y);
    pk.y = cvt_pk_bf16(v.z, v.w);
    *reinterpret_cast<uint2*>(&out[i]) = pk;
}

// ---------------------------------------------------------------------------
// bf16 MFMA GEMM: C[M,N] = A[M,K] * B[N,K]^T + bias[N]
// MODE 0: fp32 output to Cout (O-projection).
// MODE 1: QKV split — cols [0,2048) bf16 to qkb (stride 2048);
//         cols [2048,3072) = V written TRANSPOSED to vtb[b*16+h][d][t].
// ---------------------------------------------------------------------------
template <int MODE>
__global__ __launch_bounds__(256) void gemm_mfma_abt(
    const ushort* __restrict__ A, const ushort* __restrict__ B,
    const float* __restrict__ bias, float* __restrict__ Cout,
    ushort* __restrict__ qkb, ushort* __restrict__ vtb,
    int M, int N, int K)
{
    __shared__ ushort Al[128 * 64];
    __shared__ ushort Bl[128 * 64];

    const int tid  = threadIdx.x;
    const int lane = tid & 63;
    const int wave = tid >> 6;
    const int wr   = wave >> 1;
    const int wc   = wave & 1;
    const int l15  = lane & 15;
    const int l4   = lane >> 4;
    const int m0   = blockIdx.y * 128;
    const int n0   = blockIdx.x * 128;

    f32x4 acc[4][4];
#pragma unroll
    for (int m = 0; m < 4; ++m)
#pragma unroll
        for (int n = 0; n < 4; ++n)
#pragma unroll
            for (int r = 0; r < 4; ++r) acc[m][n][r] = 0.f;

    for (int k0 = 0; k0 < K; k0 += 64) {
#pragma unroll
        for (int it = 0; it < 4; ++it) {
            int chunk = tid + it * 256;
            int row = chunk >> 3;
            int kc  = (chunk & 7) * 8;
            gload_lds16(&A[(size_t)(m0 + row) * K + k0 + kc], &Al[chunk * 8]);
            gload_lds16(&B[(size_t)(n0 + row) * K + k0 + kc], &Bl[chunk * 8]);
        }
        __syncthreads();

#pragma unroll
        for (int kk = 0; kk < 2; ++kk) {
            const int ko = kk * 32 + l4 * 8;
            bf16x8 a[4], b[4];
#pragma unroll
            for (int m = 0; m < 4; ++m)
                a[m] = *reinterpret_cast<const bf16x8*>(
                    &Al[(wr * 64 + m * 16 + l15) * 64 + ko]);
#pragma unroll
            for (int n = 0; n < 4; ++n)
                b[n] = *reinterpret_cast<const bf16x8*>(
                    &Bl[(wc * 64 + n * 16 + l15) * 64 + ko]);
            __builtin_amdgcn_s_setprio(1);
#pragma unroll
            for (int m = 0; m < 4; ++m)
#pragma unroll
                for (int n = 0; n < 4; ++n)
                    acc[m][n] = __builtin_amdgcn_mfma_f32_16x16x32_bf16(
                        a[m], b[n], acc[m][n], 0, 0, 0);
            __builtin_amdgcn_s_setprio(0);
        }
        __syncthreads();
    }

    // epilogue; C/D: col = lane&15, row = (lane>>4)*4 + reg (verified)
#pragma unroll
    for (int n = 0; n < 4; ++n) {
        const int col = n0 + wc * 64 + n * 16 + l15;
        const float bv = bias[col];
        if (MODE == 0) {
#pragma unroll
            for (int m = 0; m < 4; ++m) {
                const int row0 = m0 + wr * 64 + m * 16 + l4 * 4;
#pragma unroll
                for (int r = 0; r < 4; ++r)
                    Cout[(size_t)(row0 + r) * N + col] = acc[m][n][r] + bv;
            }
        } else if (col < 2 * EMB) {
            // Q/K part, row-major bf16, stride 2048
#pragma unroll
            for (int m = 0; m < 4; ++m) {
                const int row0 = m0 + wr * 64 + m * 16 + l4 * 4;
#pragma unroll
                for (int r = 0; r < 4; ++r)
                    qkb[(size_t)(row0 + r) * 2048 + col] = f2bf(acc[m][n][r] + bv);
            }
        } else {
            // V part, transposed: vtb[(b*16+h)*64 + d][t], t = row
            const int h = (col - 2 * EMB) >> 6;
            const int d = col & 63;
#pragma unroll
            for (int m = 0; m < 4; ++m) {
                const int row0 = m0 + wr * 64 + m * 16 + l4 * 4;
                const int bb = row0 >> 11;
                const int t  = row0 & 2047;
                uint2 pk;
                pk.x = cvt_pk_bf16(acc[m][n][0] + bv, acc[m][n][1] + bv);
                pk.y = cvt_pk_bf16(acc[m][n][2] + bv, acc[m][n][3] + bv);
                *reinterpret_cast<uint2*>(
                    &vtb[((size_t)(bb * 16 + h) * 64 + d) * 2048 + t]) = pk;
            }
        }
    }
}

// ---------------------------------------------------------------------------
// MFMA flash attention, swapped-QK softmax. SPLIT-KV HELPER-WAVE blocks:
// 1024 threads (16 waves), block = (bh, pp); q-tiles A=pp, B=15-pp.
// B-waves (8..15): B's kv HEAD, tiles 0..16.
// A-waves (0..7):  A's full kv (tiles 0..2pp+1), then HELP with B's kv TAIL
//                  (tiles 17..31-2pp). Both paths = 17 iterations exactly ->
//                  every wave, every block uniform. A output written at the
//                  (wave-uniform) switch; B head+tail merged at the end via
//                  the standard flash combine through LDS.
// kv staging: front stream (tid<512) + tail stream (tid>=512), dbuf each.
// All LDS rows 128B, XOR-swizzled by ((row&7)<<4) bytes (pre-swizzled source).
// ---------------------------------------------------------------------------
__global__ __launch_bounds__(1024) void attn_mfma(
    const ushort* __restrict__ qk, const ushort* __restrict__ vt,
    ushort* __restrict__ y)
{
    __shared__ alignas(16) ushort KV[8][4096];  // K slots 0,1(front) 2,3(tail); V = 4+slot
    __shared__ alignas(16) ushort QP[16384];    // 256 rows x 64 (Q both tiles -> P regions)

    const int tid  = threadIdx.x;
    const int lane = tid & 63;
    const int w    = tid >> 6;     // wave 0..15
    const int u    = w & 7;        // unit within group
    const bool isA = (w < 8);
    const int l15  = lane & 15;
    const int l4   = lane >> 4;

    const int id  = blockIdx.x;                   // 0..255
    const int xcd = id & 7;
    const int bh  = xcd * 4 + ((id >> 3) & 3);    // 0..31 (4 bh per XCD)
    const int pp  = id >> 5;                      // 0..7
    const int qtA = pp, qtB = 15 - pp;
    const int nkvA = 2 * pp + 2;                  // 2..16
    const int nkvB = 32 - 2 * pp;                 // 18..32
    const int b   = bh >> 4;
    const int h   = bh & 15;

    const ushort* qbase = qk + (size_t)b * SEQ * 2048 + h * HD;
    const ushort* kbase = qbase + EMB;
    const ushort* vbase = vt + (size_t)bh * HD * SEQ;        // [d][t]

    const int swz   = (l15 & 7) << 4;
    const int koff0 = ((l4 * 16) ^ swz) >> 1;        // ushort units
    const int koff1 = ((64 + l4 * 16) ^ swz) >> 1;
    int pso[4];
#pragma unroll
    for (int n = 0; n < 4; ++n) pso[n] = ((n * 32 + l4 * 8) ^ swz) >> 1;

    const short OBF = (short)0x3F80;   // 1.0 bf16
    const bf16x8 ones = {OBF, OBF, OBF, OBF, OBF, OBF, OBF, OBF};
    const float BETA = 0.18033688f;    // 0.125 * log2(e)

    const int qrow = (w * 16 + l15) * 64;   // private Q/P region row base

    // staging coordinates (one 16B chunk per half-block thread per 64x64 tile)
    const int st = tid & 511;
    const int fr = st >> 3;                           // row 0..63
    const int fc = ((st & 7) ^ (fr & 7)) << 3;        // swizzled col

    // ---- prologue: stage Q (both tiles) + front tile 0 ----
#pragma unroll
    for (int it = 0; it < 2; ++it) {
        int c = tid + it * 1024;             // 0..2047
        int qs = c >> 10;                    // 0: tile A, 1: tile B
        int r  = (c >> 3) & 127;
        int cc = ((c & 7) ^ (r & 7)) << 3;
        int grow = (qs ? qtB : qtA) * 128 + r;
        gload_lds16(qbase + (size_t)grow * 2048 + cc, &QP[c * 8]);
    }
    if (tid < 512) {
        gload_lds16(kbase + (size_t)fr * 2048 + fc, &KV[0][st * 8]);
        gload_lds16(vbase + (size_t)fr * 2048 + fc, &KV[4][st * 8]);
    }
    __syncthreads();

    // Q fragments (A-waves keep BOTH tiles' frags; loaded before any P write)
    bf16x8 qfA0, qfA1, qfB0, qfB1;
    if (isA) {
        qfA0 = *reinterpret_cast<const bf16x8*>(&QP[(u * 16 + l15) * 64 + koff0]);
        qfA1 = *reinterpret_cast<const bf16x8*>(&QP[(u * 16 + l15) * 64 + koff1]);
    }
    qfB0 = *reinterpret_cast<const bf16x8*>(&QP[(128 + u * 16 + l15) * 64 + koff0]);
    qfB1 = *reinterpret_cast<const bf16x8*>(&QP[(128 + u * 16 + l15) * 64 + koff1]);
    __syncthreads();   // frags in regs before any wave's P overwrites Q rows

    f32x4 o[4];
    f32x4 lacc;
    float m;
#pragma unroll
    for (int n = 0; n < 4; ++n)
#pragma unroll
        for (int r = 0; r < 4; ++r) o[n][r] = 0.f;
    lacc[0] = lacc[1] = lacc[2] = lacc[3] = 0.f;
    m = -3.0e38f;

    auto writeOut = [&](int qtile) {
#pragma unroll
        for (int r = 0; r < 4; ++r) {
            float inv = 1.f / lacc[r];
            int row = qtile * 128 + u * 16 + l4 * 4 + r;
#pragma unroll
            for (int n = 0; n < 4; ++n) {
                y[(size_t)(b * SEQ + row) * EMB + h * HD + n * 16 + l15] =
                    f2bf(o[n][r] * inv);
            }
        }
    };

    auto computeTile = [&](const ushort* Kb, const ushort* Vb, int tile,
                           int nkvL, int q0, const bf16x8& qf0, const bf16x8& qf1) {
        bf16x8 kf[4][2];
#pragma unroll
        for (int n = 0; n < 4; ++n) {
            kf[n][0] = *reinterpret_cast<const bf16x8*>(
                &Kb[(n * 16 + l15) * 64 + koff0]);
            kf[n][1] = *reinterpret_cast<const bf16x8*>(
                &Kb[(n * 16 + l15) * 64 + koff1]);
        }
        f32x4 s[4];
        __builtin_amdgcn_s_setprio(1);
#pragma unroll
        for (int n = 0; n < 4; ++n) {
            f32x4 z = {0.f, 0.f, 0.f, 0.f};
            z = __builtin_amdgcn_mfma_f32_16x16x32_bf16(kf[n][0], qf0, z, 0, 0, 0);
            s[n] = __builtin_amdgcn_mfma_f32_16x16x32_bf16(kf[n][1], qf1, z, 0, 0, 0);
        }
        __builtin_amdgcn_s_setprio(0);

        bf16x8 vf[4][2];
#pragma unroll
        for (int n = 0; n < 4; ++n) {
            vf[n][0] = *reinterpret_cast<const bf16x8*>(
                &Vb[(n * 16 + l15) * 64 + koff0]);
            vf[n][1] = *reinterpret_cast<const bf16x8*>(
                &Vb[(n * 16 + l15) * 64 + koff1]);
        }

        // causal mask: only the unit's last two kv tiles can violate causality
        if (tile >= nkvL - 2) {
#pragma unroll
            for (int n = 0; n < 4; ++n)
#pragma unroll
                for (int r = 0; r < 4; ++r) {
                    int kg = tile * 64 + n * 16 + l4 * 4 + r;
                    if (kg > q0) s[n][r] = -3.0e38f;
                }
        }

        // per-lane partial max (tree) -> conservative rescale check
        float a0 = fmaxf(fmaxf(s[0][0], s[0][1]), fmaxf(s[0][2], s[0][3]));
        float a1 = fmaxf(fmaxf(s[1][0], s[1][1]), fmaxf(s[1][2], s[1][3]));
        float a2 = fmaxf(fmaxf(s[2][0], s[2][1]), fmaxf(s[2][2], s[2][3]));
        float a3 = fmaxf(fmaxf(s[3][0], s[3][1]), fmaxf(s[3][2], s[3][3]));
        float pm = fmaxf(fmaxf(a0, a1), fmaxf(a2, a3)) * BETA;

        // defer-max rescale (rare, wave-uniform); ballot covers all (k,q)
        if (__any(pm > m + 8.0f)) {
            float tm = fmaxf(pm, __shfl_xor(pm, 16));
            tm = fmaxf(tm, __shfl_xor(tm, 32));
            float mn = fmaxf(m, tm);
            float al = exp2f(m - mn);
            m = mn;
            float b0 = __shfl(al, l4 * 4 + 0, 16);
            float b1 = __shfl(al, l4 * 4 + 1, 16);
            float b2 = __shfl(al, l4 * 4 + 2, 16);
            float b3 = __shfl(al, l4 * 4 + 3, 16);
            lacc[0] *= b0; lacc[1] *= b1; lacc[2] *= b2; lacc[3] *= b3;
#pragma unroll
            for (int n = 0; n < 4; ++n) {
                o[n][0] *= b0; o[n][1] *= b1; o[n][2] *= b2; o[n][3] *= b3;
            }
        }

        // p = 2^(s*BETA - m), pack + store P (wave-private rows)
#pragma unroll
        for (int n = 0; n < 4; ++n) {
            float pa = exp2f(fmaf(s[n][0], BETA, -m));
            float pb = exp2f(fmaf(s[n][1], BETA, -m));
            float pc = exp2f(fmaf(s[n][2], BETA, -m));
            float pd = exp2f(fmaf(s[n][3], BETA, -m));
            uint2 pk;
            pk.x = cvt_pk_bf16(pa, pb);
            pk.y = cvt_pk_bf16(pc, pd);
            *reinterpret_cast<uint2*>(&QP[qrow + pso[n]]) = pk;
        }

        // O += P V, l += P·1
        bf16x8 pf0 = *reinterpret_cast<const bf16x8*>(&QP[qrow + koff0]);
        bf16x8 pf1 = *reinterpret_cast<const bf16x8*>(&QP[qrow + koff1]);
        __builtin_amdgcn_s_setprio(1);
        lacc = __builtin_amdgcn_mfma_f32_16x16x32_bf16(pf0, ones, lacc, 0, 0, 0);
        lacc = __builtin_amdgcn_mfma_f32_16x16x32_bf16(pf1, ones, lacc, 0, 0, 0);
#pragma unroll
        for (int n = 0; n < 4; ++n) {
            o[n] = __builtin_amdgcn_mfma_f32_16x16x32_bf16(pf0, vf[n][0], o[n], 0, 0, 0);
            o[n] = __builtin_amdgcn_mfma_f32_16x16x32_bf16(pf1, vf[n][1], o[n], 0, 0, 0);
        }
        __builtin_amdgcn_s_setprio(0);
    };

    // ---- main loop: 17 uniform iterations ----
    for (int i = 0; i < 17; ++i) {
        // stage tiles for iter i+1 (front by tid<512, tail by tid>=512)
        if (i < 16) {
            int nf = i + 1;
            if (tid < 512) {
                gload_lds16(kbase + (size_t)(nf * 64 + fr) * 2048 + fc,
                            &KV[nf & 1][st * 8]);
                gload_lds16(vbase + (size_t)fr * 2048 + nf * 64 + fc,
                            &KV[4 + (nf & 1)][st * 8]);
            } else if (nf >= nkvA) {
                int tt = 17 + (nf - nkvA);            // <= nkvB-1
                gload_lds16(kbase + (size_t)(tt * 64 + fr) * 2048 + fc,
                            &KV[2 + (tt & 1)][st * 8]);
                gload_lds16(vbase + (size_t)fr * 2048 + tt * 64 + fc,
                            &KV[6 + (tt & 1)][st * 8]);
            }
        }

        if (isA) {
            if (i == nkvA) {   // wave-uniform switch: A done -> write + reset
                writeOut(qtA);
#pragma unroll
                for (int n = 0; n < 4; ++n)
#pragma unroll
                    for (int r = 0; r < 4; ++r) o[n][r] = 0.f;
                lacc[0] = lacc[1] = lacc[2] = lacc[3] = 0.f;
                m = -3.0e38f;
            }
            if (i < nkvA) {
                computeTile(KV[i & 1], KV[4 + (i & 1)], i, nkvA,
                            qtA * 128 + u * 16 + l15, qfA0, qfA1);
            } else {
                int tt = 17 + (i - nkvA);
                computeTile(KV[2 + (tt & 1)], KV[6 + (tt & 1)], tt, nkvB,
                            qtB * 128 + u * 16 + l15, qfB0, qfB1);
            }
        } else {
            computeTile(KV[i & 1], KV[4 + (i & 1)], i, nkvB,
                        qtB * 128 + u * 16 + l15, qfB0, qfB1);
        }
        __syncthreads();
    }

    // ---- merge: A-waves publish B-tail state; B-waves combine + write ----
    float* mbuf = reinterpret_cast<float*>(&KV[0][0]);   // 43 KB of 64 KB
    if (isA) {
        int base = (u * 64 + lane) * 21;   // stride 21 coprime to 32: no conflicts
#pragma unroll
        for (int n = 0; n < 4; ++n)
#pragma unroll
            for (int r = 0; r < 4; ++r) mbuf[base + n * 4 + r] = o[n][r];
#pragma unroll
        for (int r = 0; r < 4; ++r) mbuf[base + 16 + r] = lacc[r];
        mbuf[base + 20] = m;
    }
    __syncthreads();
    if (!isA) {
        int base = (u * 64 + lane) * 21;
        float mt = mbuf[base + 20];
        float M  = fmaxf(m, mt);
        float fh = exp2f(m - M);
        float ft = exp2f(mt - M);
#pragma unroll
        for (int r = 0; r < 4; ++r) {
            float fhr = __shfl(fh, l4 * 4 + r, 16);
            float ftr = __shfl(ft, l4 * 4 + r, 16);
            lacc[r] = lacc[r] * fhr + mbuf[base + 16 + r] * ftr;
#pragma unroll
            for (int n = 0; n < 4; ++n)
                o[n][r] = o[n][r] * fhr + mbuf[base + n * 4 + r] * ftr;
        }
        writeOut(qtB);
    }
}

// ---------------------------------------------------------------------------
extern "C" void kernel_launch(void* const* d_in, const int* in_sizes, int n_in,
                              void* d_out, int out_size, void* d_ws, size_t ws_size,
                              hipStream_t stream)
{
    const float* x     = (const float*)d_in[0];   // [B,T,E]
    const float* qkv_w = (const float*)d_in[1];   // [3E,E]
    const float* qkv_b = (const float*)d_in[2];   // [3E]
    const float* o_w   = (const float*)d_in[3];   // [E,E]
    const float* o_b   = (const float*)d_in[4];   // [E]
    float* out = (float*)d_out;                   // [B,T,E] fp32

    // workspace (ushort units)
    ushort* xb    = (ushort*)d_ws;                       // 4M
    ushort* wqkvb = xb    + (size_t)M_ROWS * EMB;        // 3M
    ushort* owb   = wqkvb + (size_t)3 * EMB * EMB;       // 1M
    ushort* qkb   = owb   + (size_t)EMB * EMB;           // 8M  [4096][2048]
    ushort* vtb   = qkb   + (size_t)M_ROWS * 2 * EMB;    // 4M  [32][64][2048]
    ushort* ybb   = vtb   + (size_t)32 * HD * SEQ;       // 4M  [4096][1024]

    // 0) fused fp32 -> bf16 (x, qkv_w, o_w -> contiguous xb/wqkvb/owb)
    {
        int n1 = M_ROWS * EMB;        // 4M
        int n2 = 3 * EMB * EMB;       // 3M
        int ntot = n1 + n2 + EMB * EMB;
        cvt3_f32_bf16<<<ntot / 1024, 256, 0, stream>>>(
            x, qkv_w, o_w, xb, n1, n2);
    }

    // 1) QKV projection, split output: Q/K row-major, V transposed
    {
        dim3 grid(3 * EMB / 128, M_ROWS / 128);   // (24, 32)
        gemm_mfma_abt<1><<<grid, 256, 0, stream>>>(
            xb, wqkvb, qkv_b, nullptr, qkb, vtb, M_ROWS, 3 * EMB, EMB);
    }

    // 2) MFMA flash attention -> ybb (bf16 [M,E]); split-kv helper waves
    {
        attn_mfma<<<256, 1024, 0, stream>>>(qkb, vtb, ybb);
    }

    // 3) Output projection (fp32 out)
    {
        dim3 grid(EMB / 128, M_ROWS / 128);       // (8, 32)
        gemm_mfma_abt<0><<<grid, 256, 0, stream>>>(
            ybb, owb, o_b, out, nullptr, nullptr, M_ROWS, EMB, EMB);
    }
}

// Round 13
// 114.806 us; speedup vs baseline: 1.0491x; 1.0491x over previous
//
#include <hip/hip_runtime.h>
#include <hip/hip_bf16.h>
#include <math.h>

// Problem constants
#define BATCH 2
#define SEQ   2048
#define EMB   1024
#define NH    16
#define HD    64
#define M_ROWS (BATCH * SEQ)   // 4096

typedef __attribute__((ext_vector_type(8))) short bf16x8;
typedef __attribute__((ext_vector_type(4))) float f32x4;

// fp32 -> bf16 round-to-nearest-even, raw bits
__device__ __forceinline__ ushort f2bf(float f) {
    unsigned u = __float_as_uint(f);
    unsigned lsb = (u >> 16) & 1u;
    u += 0x7fffu + lsb;
    return (ushort)(u >> 16);
}

// packed f32 pair -> 2 bf16 in one u32 (RNE), single VALU op
__device__ __forceinline__ unsigned cvt_pk_bf16(float lo, float hi) {
    unsigned r;
    asm("v_cvt_pk_bf16_f32 %0, %1, %2" : "=v"(r) : "v"(lo), "v"(hi));
    return r;
}

__device__ __forceinline__ void gload_lds16(const void* g, void* l) {
    __builtin_amdgcn_global_load_lds(
        (const __attribute__((address_space(1))) unsigned int*)g,
        (__attribute__((address_space(3))) unsigned int*)l, 16, 0, 0);
}

// ---------------------------------------------------------------------------
// fused fp32 -> bf16 conversion of x, qkv_w, o_w (outputs contiguous in ws)
// ---------------------------------------------------------------------------
__global__ __launch_bounds__(256) void cvt3_f32_bf16(
    const float* __restrict__ s1, const float* __restrict__ s2,
    const float* __restrict__ s3, ushort* __restrict__ out,
    int n1, int n2)
{
    int i = (blockIdx.x * 256 + threadIdx.x) * 4;
    const float* src;
    int off;
    if (i < n1)            { src = s1; off = i; }
    else if (i < n1 + n2)  { src = s2; off = i - n1; }
    else                   { src = s3; off = i - n1 - n2; }
    float4 v = *reinterpret_cast<const float4*>(&src[off]);
    uint2 pk;
    pk.x = cvt_pk_bf16(v.x, v.y);
    pk.y = cvt_pk_bf16(v.z, v.w);
    *reinterpret_cast<uint2*>(&out[i]) = pk;
}

// ---------------------------------------------------------------------------
// bf16 MFMA GEMM: C[M,N] = A[M,K] * B[N,K]^T + bias[N]
// MODE 0: fp32 output to Cout (O-projection).
// MODE 1: QKV split — cols [0,1024) = Q, scaled by BETA=0.125*log2(e) (the
//         attention softmax works in the log2 domain on pre-scaled Q);
//         cols [0,2048) bf16 to qkb (stride 2048);
//         cols [2048,3072) = V written TRANSPOSED to vtb[b*16+h][d][t].
// ---------------------------------------------------------------------------
template <int MODE>
__global__ __launch_bounds__(256) void gemm_mfma_abt(
    const ushort* __restrict__ A, const ushort* __restrict__ B,
    const float* __restrict__ bias, float* __restrict__ Cout,
    ushort* __restrict__ qkb, ushort* __restrict__ vtb,
    int M, int N, int K)
{
    __shared__ ushort Al[128 * 64];
    __shared__ ushort Bl[128 * 64];

    const int tid  = threadIdx.x;
    const int lane = tid & 63;
    const int wave = tid >> 6;
    const int wr   = wave >> 1;
    const int wc   = wave & 1;
    const int l15  = lane & 15;
    const int l4   = lane >> 4;
    const int m0   = blockIdx.y * 128;
    const int n0   = blockIdx.x * 128;

    f32x4 acc[4][4];
#pragma unroll
    for (int m = 0; m < 4; ++m)
#pragma unroll
        for (int n = 0; n < 4; ++n)
#pragma unroll
            for (int r = 0; r < 4; ++r) acc[m][n][r] = 0.f;

    for (int k0 = 0; k0 < K; k0 += 64) {
#pragma unroll
        for (int it = 0; it < 4; ++it) {
            int chunk = tid + it * 256;
            int row = chunk >> 3;
            int kc  = (chunk & 7) * 8;
            gload_lds16(&A[(size_t)(m0 + row) * K + k0 + kc], &Al[chunk * 8]);
            gload_lds16(&B[(size_t)(n0 + row) * K + k0 + kc], &Bl[chunk * 8]);
        }
        __syncthreads();

#pragma unroll
        for (int kk = 0; kk < 2; ++kk) {
            const int ko = kk * 32 + l4 * 8;
            bf16x8 a[4], b[4];
#pragma unroll
            for (int m = 0; m < 4; ++m)
                a[m] = *reinterpret_cast<const bf16x8*>(
                    &Al[(wr * 64 + m * 16 + l15) * 64 + ko]);
#pragma unroll
            for (int n = 0; n < 4; ++n)
                b[n] = *reinterpret_cast<const bf16x8*>(
                    &Bl[(wc * 64 + n * 16 + l15) * 64 + ko]);
            __builtin_amdgcn_s_setprio(1);
#pragma unroll
            for (int m = 0; m < 4; ++m)
#pragma unroll
                for (int n = 0; n < 4; ++n)
                    acc[m][n] = __builtin_amdgcn_mfma_f32_16x16x32_bf16(
                        a[m], b[n], acc[m][n], 0, 0, 0);
            __builtin_amdgcn_s_setprio(0);
        }
        __syncthreads();
    }

    // epilogue; C/D: col = lane&15, row = (lane>>4)*4 + reg (verified)
#pragma unroll
    for (int n = 0; n < 4; ++n) {
        const int col = n0 + wc * 64 + n * 16 + l15;
        const float bv = bias[col];
        if (MODE == 0) {
#pragma unroll
            for (int m = 0; m < 4; ++m) {
                const int row0 = m0 + wr * 64 + m * 16 + l4 * 4;
#pragma unroll
                for (int r = 0; r < 4; ++r)
                    Cout[(size_t)(row0 + r) * N + col] = acc[m][n][r] + bv;
            }
        } else if (col < 2 * EMB) {
            // Q/K part, row-major bf16, stride 2048. Q pre-scaled by BETA.
            const float qs = (col < EMB) ? 0.18033688f : 1.0f;
#pragma unroll
            for (int m = 0; m < 4; ++m) {
                const int row0 = m0 + wr * 64 + m * 16 + l4 * 4;
#pragma unroll
                for (int r = 0; r < 4; ++r)
                    qkb[(size_t)(row0 + r) * 2048 + col] =
                        f2bf((acc[m][n][r] + bv) * qs);
            }
        } else {
            // V part, transposed: vtb[(b*16+h)*64 + d][t], t = row
            const int h = (col - 2 * EMB) >> 6;
            const int d = col & 63;
#pragma unroll
            for (int m = 0; m < 4; ++m) {
                const int row0 = m0 + wr * 64 + m * 16 + l4 * 4;
                const int bb = row0 >> 11;
                const int t  = row0 & 2047;
                uint2 pk;
                pk.x = cvt_pk_bf16(acc[m][n][0] + bv, acc[m][n][1] + bv);
                pk.y = cvt_pk_bf16(acc[m][n][2] + bv, acc[m][n][3] + bv);
                *reinterpret_cast<uint2*>(
                    &vtb[((size_t)(bb * 16 + h) * 64 + d) * 2048 + t]) = pk;
            }
        }
    }
}

// ---------------------------------------------------------------------------
// MFMA flash attention, swapped-QK softmax. UNIFORM-WORK blocks (round-11
// structure): 512 threads (8 waves); block = (bh, pair p); processes q-tiles
// qt=p and qt=15-p SEQUENTIALLY -> every block runs exactly 34 kv-tile
// iterations. Grid 256 = 1 block/CU, no imbalance tail.
// OCT-buffered K/V (tile t -> slot t&7); 4 kv-tiles per barrier window:
// stage kk+4..kk+7, compute kk..kk+3, one barrier. Q pre-scaled by BETA so
// scores are already log2-domain (no per-element scale in the hot loop).
// Critical-path-lean softmax (per-lane partial max + ballot; l via MFMA-ones).
// ---------------------------------------------------------------------------
__global__ __launch_bounds__(512) void attn_mfma(
    const ushort* __restrict__ qk, const ushort* __restrict__ vt,
    ushort* __restrict__ y)
{
    __shared__ alignas(16) ushort Kl[8][4096];
    __shared__ alignas(16) ushort Vl[8][4096];
    __shared__ alignas(16) ushort QP[8192];     // 128 rows x 64

    const int tid  = threadIdx.x;
    const int lane = tid & 63;
    const int w    = tid >> 6;     // wave 0..7
    const int l15  = lane & 15;
    const int l4   = lane >> 4;

    // block -> (bh, pair): 4 consecutive bh per XCD
    const int id  = blockIdx.x;                   // 0..255
    const int xcd = id & 7;
    const int bh  = xcd * 4 + ((id >> 3) & 3);    // 0..31
    const int pp  = id >> 5;                      // pair 0..7
    const int b   = bh >> 4;
    const int h   = bh & 15;

    const ushort* qbase = qk + (size_t)b * SEQ * 2048 + h * HD;
    const ushort* kbase = qbase + EMB;
    const ushort* vbase = vt + (size_t)bh * HD * SEQ;        // [d][t]

    const int swz   = (l15 & 7) << 4;
    const int koff0 = ((l4 * 16) ^ swz) >> 1;        // ushort units
    const int koff1 = ((64 + l4 * 16) ^ swz) >> 1;

    int pso[4];
#pragma unroll
    for (int n = 0; n < 4; ++n) pso[n] = ((n * 32 + l4 * 8) ^ swz) >> 1;

    const short OBF = (short)0x3F80;   // 1.0 bf16
    const bf16x8 ones = {OBF, OBF, OBF, OBF, OBF, OBF, OBF, OBF};

    const int qrow = (w * 16 + l15) * 64;    // wave-local Q/P row base

    // staging coordinates (one 16B chunk per thread per 64x64 tile)
    const int sr = tid >> 3;                          // row 0..63
    const int sc = ((tid & 7) ^ (sr & 7)) << 3;       // swizzled col
    const int i2 = tid + 512;
    const int qr2 = i2 >> 3;
    const int qc2 = ((i2 & 7) ^ (qr2 & 7)) << 3;

#pragma unroll
    for (int pass = 0; pass < 2; ++pass) {
        const int qt  = pass ? (15 - pp) : pp;
        const int nkv = 2 * qt + 2;

        // ---- prologue: stage Q (128x64) + kv tiles 0..3 ----
        gload_lds16(qbase + (size_t)(qt * 128 + sr) * 2048 + sc, &QP[tid * 8]);
        gload_lds16(qbase + (size_t)(qt * 128 + qr2) * 2048 + qc2, &QP[i2 * 8]);
#pragma unroll
        for (int t = 0; t < 4; ++t) {
            gload_lds16(kbase + (size_t)(t * 64 + sr) * 2048 + sc, &Kl[t][tid * 8]);
            gload_lds16(vbase + (size_t)sr * 2048 + t * 64 + sc, &Vl[t][tid * 8]);
        }
        __syncthreads();

        const bf16x8 qf0 = *reinterpret_cast<const bf16x8*>(&QP[qrow + koff0]);
        const bf16x8 qf1 = *reinterpret_cast<const bf16x8*>(&QP[qrow + koff1]);

        f32x4 o[4];
#pragma unroll
        for (int n = 0; n < 4; ++n)
#pragma unroll
            for (int r = 0; r < 4; ++r) o[n][r] = 0.f;
        f32x4 lacc = {0.f, 0.f, 0.f, 0.f};
        float m = -3.0e38f;

        auto computeTile = [&](const ushort* Kb, const ushort* Vb, int kkt) {
            bf16x8 kf[4][2];
#pragma unroll
            for (int n = 0; n < 4; ++n) {
                kf[n][0] = *reinterpret_cast<const bf16x8*>(
                    &Kb[(n * 16 + l15) * 64 + koff0]);
                kf[n][1] = *reinterpret_cast<const bf16x8*>(
                    &Kb[(n * 16 + l15) * 64 + koff1]);
            }
            f32x4 s[4];
            __builtin_amdgcn_s_setprio(1);
#pragma unroll
            for (int n = 0; n < 4; ++n) {
                f32x4 z = {0.f, 0.f, 0.f, 0.f};
                z = __builtin_amdgcn_mfma_f32_16x16x32_bf16(kf[n][0], qf0, z, 0, 0, 0);
                s[n] = __builtin_amdgcn_mfma_f32_16x16x32_bf16(kf[n][1], qf1, z, 0, 0, 0);
            }
            __builtin_amdgcn_s_setprio(0);

            bf16x8 vf[4][2];
#pragma unroll
            for (int n = 0; n < 4; ++n) {
                vf[n][0] = *reinterpret_cast<const bf16x8*>(
                    &Vb[(n * 16 + l15) * 64 + koff0]);
                vf[n][1] = *reinterpret_cast<const bf16x8*>(
                    &Vb[(n * 16 + l15) * 64 + koff1]);
            }

            // causal mask: only the last two kv tiles can violate causality
            if (kkt >= nkv - 2) {
                const int q0 = qt * 128 + w * 16 + l15;
#pragma unroll
                for (int n = 0; n < 4; ++n)
#pragma unroll
                    for (int r = 0; r < 4; ++r) {
                        int kg = kkt * 64 + n * 16 + l4 * 4 + r;
                        if (kg > q0) s[n][r] = -3.0e38f;
                    }
            }

            // per-lane partial max (tree); scores already log2-domain
            float a0 = fmaxf(fmaxf(s[0][0], s[0][1]), fmaxf(s[0][2], s[0][3]));
            float a1 = fmaxf(fmaxf(s[1][0], s[1][1]), fmaxf(s[1][2], s[1][3]));
            float a2 = fmaxf(fmaxf(s[2][0], s[2][1]), fmaxf(s[2][2], s[2][3]));
            float a3 = fmaxf(fmaxf(s[3][0], s[3][1]), fmaxf(s[3][2], s[3][3]));
            float pm = fmaxf(fmaxf(a0, a1), fmaxf(a2, a3));

            // defer-max rescale (rare, wave-uniform); ballot covers all (k,q)
            if (__any(pm > m + 8.0f)) {
                float tm = fmaxf(pm, __shfl_xor(pm, 16));
                tm = fmaxf(tm, __shfl_xor(tm, 32));
                float mn = fmaxf(m, tm);
                float al = exp2f(m - mn);
                m = mn;
                float b0 = __shfl(al, l4 * 4 + 0, 16);
                float b1 = __shfl(al, l4 * 4 + 1, 16);
                float b2 = __shfl(al, l4 * 4 + 2, 16);
                float b3 = __shfl(al, l4 * 4 + 3, 16);
                lacc[0] *= b0; lacc[1] *= b1; lacc[2] *= b2; lacc[3] *= b3;
#pragma unroll
                for (int n = 0; n < 4; ++n) {
                    o[n][0] *= b0; o[n][1] *= b1; o[n][2] *= b2; o[n][3] *= b3;
                }
            }

            // p = 2^(s - m), pack + store P (wave-local rows)
#pragma unroll
            for (int n = 0; n < 4; ++n) {
                float pa = exp2f(s[n][0] - m);
                float pb = exp2f(s[n][1] - m);
                float pc = exp2f(s[n][2] - m);
                float pd = exp2f(s[n][3] - m);
                uint2 pk;
                pk.x = cvt_pk_bf16(pa, pb);
                pk.y = cvt_pk_bf16(pc, pd);
                *reinterpret_cast<uint2*>(&QP[qrow + pso[n]]) = pk;
            }

            // O += P V, l += P·1
            bf16x8 pf0 = *reinterpret_cast<const bf16x8*>(&QP[qrow + koff0]);
            bf16x8 pf1 = *reinterpret_cast<const bf16x8*>(&QP[qrow + koff1]);
            __builtin_amdgcn_s_setprio(1);
            lacc = __builtin_amdgcn_mfma_f32_16x16x32_bf16(pf0, ones, lacc, 0, 0, 0);
            lacc = __builtin_amdgcn_mfma_f32_16x16x32_bf16(pf1, ones, lacc, 0, 0, 0);
#pragma unroll
            for (int n = 0; n < 4; ++n) {
                o[n] = __builtin_amdgcn_mfma_f32_16x16x32_bf16(pf0, vf[n][0], o[n], 0, 0, 0);
                o[n] = __builtin_amdgcn_mfma_f32_16x16x32_bf16(pf1, vf[n][1], o[n], 0, 0, 0);
            }
            __builtin_amdgcn_s_setprio(0);
        };

        // ---- main loop: 4 tiles per barrier window ----
        for (int kk = 0; kk < nkv; kk += 4) {
            // stage window kk+4..kk+7 (slots (t)&7, disjoint from compute slots)
#pragma unroll
            for (int j = 0; j < 4; ++j) {
                int t = kk + 4 + j;
                if (t < nkv) {
                    gload_lds16(kbase + (size_t)(t * 64 + sr) * 2048 + sc,
                                &Kl[t & 7][tid * 8]);
                    gload_lds16(vbase + (size_t)sr * 2048 + t * 64 + sc,
                                &Vl[t & 7][tid * 8]);
                }
            }
            // compute tiles kk..kk+3
#pragma unroll
            for (int j = 0; j < 4; ++j) {
                int t = kk + j;
                if (t < nkv) computeTile(Kl[t & 7], Vl[t & 7], t);
            }
            __syncthreads();
        }

        // epilogue: O rows q = w*16 + l4*4 + r, cols d = n*16 + l15
#pragma unroll
        for (int r = 0; r < 4; ++r) {
            float inv = 1.f / lacc[r];
            int row = qt * 128 + w * 16 + l4 * 4 + r;
#pragma unroll
            for (int n = 0; n < 4; ++n) {
                y[(size_t)(b * SEQ + row) * EMB + h * HD + n * 16 + l15] =
                    f2bf(o[n][r] * inv);
            }
        }
        __syncthreads();   // LDS safe before next pass's prologue
    }
}

// ---------------------------------------------------------------------------
extern "C" void kernel_launch(void* const* d_in, const int* in_sizes, int n_in,
                              void* d_out, int out_size, void* d_ws, size_t ws_size,
                              hipStream_t stream)
{
    const float* x     = (const float*)d_in[0];   // [B,T,E]
    const float* qkv_w = (const float*)d_in[1];   // [3E,E]
    const float* qkv_b = (const float*)d_in[2];   // [3E]
    const float* o_w   = (const float*)d_in[3];   // [E,E]
    const float* o_b   = (const float*)d_in[4];   // [E]
    float* out = (float*)d_out;                   // [B,T,E] fp32

    // workspace (ushort units)
    ushort* xb    = (ushort*)d_ws;                       // 4M
    ushort* wqkvb = xb    + (size_t)M_ROWS * EMB;        // 3M
    ushort* owb   = wqkvb + (size_t)3 * EMB * EMB;       // 1M
    ushort* qkb   = owb   + (size_t)EMB * EMB;           // 8M  [4096][2048]
    ushort* vtb   = qkb   + (size_t)M_ROWS * 2 * EMB;    // 4M  [32][64][2048]
    ushort* ybb   = vtb   + (size_t)32 * HD * SEQ;       // 4M  [4096][1024]

    // 0) fused fp32 -> bf16 (x, qkv_w, o_w -> contiguous xb/wqkvb/owb)
    {
        int n1 = M_ROWS * EMB;        // 4M
        int n2 = 3 * EMB * EMB;       // 3M
        int ntot = n1 + n2 + EMB * EMB;
        cvt3_f32_bf16<<<ntot / 1024, 256, 0, stream>>>(
            x, qkv_w, o_w, xb, n1, n2);
    }

    // 1) QKV projection, split output: Q (BETA-scaled)/K row-major, V transposed
    {
        dim3 grid(3 * EMB / 128, M_ROWS / 128);   // (24, 32)
        gemm_mfma_abt<1><<<grid, 256, 0, stream>>>(
            xb, wqkvb, qkv_b, nullptr, qkb, vtb, M_ROWS, 3 * EMB, EMB);
    }

    // 2) MFMA flash attention -> ybb (bf16 [M,E]); uniform-work blocks
    {
        attn_mfma<<<256, 512, 0, stream>>>(qkb, vtb, ybb);
    }

    // 3) Output projection (fp32 out)
    {
        dim3 grid(EMB / 128, M_ROWS / 128);       // (8, 32)
        gemm_mfma_abt<0><<<grid, 256, 0, stream>>>(
            ybb, owb, o_b, out, nullptr, nullptr, M_ROWS, EMB, EMB);
    }
}